// Round 12
// baseline (343.924 us; speedup 1.0000x reference)
//
#include <hip/hip_runtime.h>
#include <stdint.h>

#define DIM 4096
#define NH 32
#define NKV 8
#define HD 128
#define SEQ 2048
#define KVD 1024  // NKV*HD

typedef unsigned short u16;
typedef __attribute__((ext_vector_type(8))) short bf16x8;   // 8 bf16 in 4 VGPRs
typedef __attribute__((ext_vector_type(4))) float f32x4;

__device__ __forceinline__ float bf2f(u16 v){
  union { unsigned u; float f; } c; c.u = ((unsigned)v) << 16; return c.f;
}
__device__ __forceinline__ u16 f2bf(float f){
  union { float f; unsigned u; } c; c.f = f;
  unsigned u = c.u;
  u += 0x7FFF + ((u >> 16) & 1);   // RNE
  return (u16)(u >> 16);
}
__device__ __forceinline__ unsigned pack2bf(float a, float b){
  return (unsigned)f2bf(a) | ((unsigned)f2bf(b) << 16);
}

__device__ __forceinline__ void gl_lds16(const void* g, void* l){
  __builtin_amdgcn_global_load_lds((const __attribute__((address_space(1))) void*)g,
                                   (__attribute__((address_space(3))) void*)l, 16, 0, 0);
}

#define VM3 asm volatile("s_waitcnt vmcnt(3)" ::: "memory")
#define VM2 asm volatile("s_waitcnt vmcnt(2)" ::: "memory")
#define VM0 asm volatile("s_waitcnt vmcnt(0)" ::: "memory")
#define LGKM0 asm volatile("s_waitcnt lgkmcnt(0)" ::: "memory")
#define SB0 __builtin_amdgcn_sched_barrier(0)
#define BAR __builtin_amdgcn_s_barrier()

// ---------------- fused fp32 -> bf16 conversion (one launch, 5 segments) -----
__global__ void cvt_all(const float* __restrict__ x,  const float* __restrict__ wq,
                        const float* __restrict__ wk, const float* __restrict__ wv,
                        const float* __restrict__ wo,
                        u16* __restrict__ xb,  u16* __restrict__ wqb,
                        u16* __restrict__ wkb, u16* __restrict__ wvb,
                        u16* __restrict__ wob){
  const int b = blockIdx.x;
  const float* in; u16* out; int base;
  if      (b <  8192){ in = x;  out = xb;  base = b; }
  else if (b < 24576){ in = wq; out = wqb; base = b - 8192; }
  else if (b < 28672){ in = wk; out = wkb; base = b - 24576; }
  else if (b < 32768){ in = wv; out = wvb; base = b - 28672; }
  else               { in = wo; out = wob; base = b - 32768; }
  const int i = (base*256 + threadIdx.x)*4;
  float4 v = *(const float4*)(in + i);
  ushort4 o;
  o.x = f2bf(v.x); o.y = f2bf(v.y); o.z = f2bf(v.z); o.w = f2bf(v.w);
  *(ushort4*)(out + i) = o;
}

// ---------------- out += partial (f32x4, exact grid) --------------------------
__global__ void add_f32(float* __restrict__ out, const float* __restrict__ p){
  const int i = blockIdx.x*256 + threadIdx.x;
  float4 a = ((const float4*)out)[i];
  const float4 b = ((const float4*)p)[i];
  a.x += b.x; a.y += b.y; a.z += b.z; a.w += b.w;
  ((float4*)out)[i] = a;
}

// ---------------- m201-style 4-phase pipelined NT GEMM ------------------------
// (unchanged from R9 - see R9 comments for the wait-slack bookkeeping)
template<int BUNITS, int EPI>
__global__ __launch_bounds__(512, 2) void gemmP(const u16* __restrict__ A,
    const u16* __restrict__ B, void* __restrict__ C0, void* __restrict__ C1,
    void* __restrict__ C2, const float* __restrict__ rf, float* __restrict__ Cp){
  constexpr int BN = BUNITS*64;
  __shared__ __align__(16) char lds[65536 + BUNITS*16384];  // A[2][256][128B] | B[2][BN][128B]
  const int t = threadIdx.x, w = t >> 6, l = t & 63;
  const int lg = l >> 4, li = l & 15;
  const int wr = w >> 2, wc = w & 3;
  const int idx = ((int)blockIdx.x & 7)*32 + ((int)blockIdx.x >> 3);  // XCD swizzle (nwg=256)

  int bm, bn, kbase, nt, ks = 0;
  if (EPI == 0){ bm = idx & 7; bn = idx >> 3; kbase = 0; nt = 64; }
  else         { bm = idx & 7; ks = (idx >> 3) & 1; bn = idx >> 4; kbase = ks*2048; nt = 32; }
  const u16* Ab = A + (size_t)bm*256*DIM;
  const u16* Bb = B + (size_t)bn*BN*DIM;

  auto stA = [&](int k0, int abase, int u){
    const int r = u*64 + (t >> 3);
    gl_lds16(Ab + (size_t)r*DIM + k0 + (((t & 7) ^ (r & 7)) << 3),
             lds + abase + u*8192 + (t >> 3)*128 + (t & 7)*16);
  };
  auto stB = [&](int k0, int bbase, int u){
    const int r = u*64 + (t >> 3);
    gl_lds16(Bb + (size_t)r*DIM + k0 + (((t & 7) ^ (r & 7)) << 3),
             lds + bbase + u*8192 + (t >> 3)*128 + (t & 7)*16);
  };

  f32x4 acc[8][BUNITS] = {};
  bf16x8 bfr[BUNITS][2];   // B-frags held across all 4 phases of a tile

#define PH(p, ...) { \
    bf16x8 af[2][2]; \
    _Pragma("unroll") \
    for (int q = 0; q < 2; ++q){ \
      const int R = wr*128 + (2*(p)+q)*16 + li; \
      af[q][0] = *(const bf16x8*)(ldsA + R*128 + (( lg    ^ (R & 7)) << 4)); \
      af[q][1] = *(const bf16x8*)(ldsA + R*128 + (((lg+4) ^ (R & 7)) << 4)); \
    } \
    if ((p) == 0){ \
      _Pragma("unroll") \
      for (int j = 0; j < BUNITS; ++j){ \
        const int R = wc*(BUNITS*16) + j*16 + li; \
        bfr[j][0] = *(const bf16x8*)(ldsB + R*128 + (( lg    ^ (R & 7)) << 4)); \
        bfr[j][1] = *(const bf16x8*)(ldsB + R*128 + (((lg+4) ^ (R & 7)) << 4)); \
      } \
    } \
    __VA_ARGS__; \
    BAR; LGKM0; SB0; \
    __builtin_amdgcn_s_setprio(1); \
    _Pragma("unroll") \
    for (int q = 0; q < 2; ++q) \
      _Pragma("unroll") \
      for (int j = 0; j < BUNITS; ++j){ \
        acc[2*(p)+q][j] = __builtin_amdgcn_mfma_f32_16x16x32_bf16(af[q][0], bfr[j][0], acc[2*(p)+q][j], 0, 0, 0); \
        acc[2*(p)+q][j] = __builtin_amdgcn_mfma_f32_16x16x32_bf16(af[q][1], bfr[j][1], acc[2*(p)+q][j], 0, 0, 0); \
      } \
    __builtin_amdgcn_s_setprio(0); \
    BAR; }

  // prologue: stage tile 0 with A1,A3 LAST; VM2 leaves {A1,A3} (the invariant)
  #pragma unroll
  for (int u = 0; u < BUNITS; ++u) stB(kbase, 65536, u);
  stA(kbase, 0, 0); stA(kbase, 0, 2);
  stA(kbase, 0, 1); stA(kbase, 0, 3);
  VM2; BAR;

  for (int tt = 0; tt < nt; ++tt){
    const int buf = tt & 1, b2 = buf ^ 1;
    const int k1 = kbase + (tt+1)*64;
    const bool pf = (tt + 1 < nt);
    const char* ldsA = lds + buf*32768;
    const char* ldsB = lds + 65536 + buf*BUNITS*8192;
    const int a2 = b2*32768, b2o = 65536 + b2*BUNITS*8192;

    PH(0, if (pf){ stB(k1, b2o, 0); stB(k1, b2o, 1); stB(k1, b2o, 2); })
    PH(1, if (pf){ VM3; if constexpr (BUNITS == 4) stB(k1, b2o, 3);
                   stA(k1, a2, 0); stA(k1, a2, 2); }
          else   { VM0; })
    PH(2, if (pf){ stA(k1, a2, 1); })
    PH(3, if (pf){ stA(k1, a2, 3); VM2; })
  }
#undef PH

  // ---------------- epilogue ----------------
  if (EPI == 1){
    float* C = (float*)(ks ? Cp : C0);
    #pragma unroll
    for (int i = 0; i < 8; ++i){
      const int srow = bm*256 + wr*128 + i*16 + lg*4;
      #pragma unroll
      for (int j = 0; j < BUNITS; ++j){
        const int col = bn*BN + wc*(BUNITS*16) + j*16 + li;
        #pragma unroll
        for (int r = 0; r < 4; ++r)
          C[(size_t)(srow + r)*DIM + col] = acc[i][j][r];
      }
    }
  } else {
    #pragma unroll
    for (int i = 0; i < 8; ++i){
      const int srow0 = bm*256 + wr*128 + i*16 + lg*4;
      #pragma unroll
      for (int j = 0; j < BUNITS; ++j){
        const int fc0 = bn*BN + wc*(BUNITS*16) + j*16;   // frag base col (16-aligned)
        const int col = fc0 + li;
        if (fc0 < 5120){                   // Q (cols<4096) or K: fused RoPE
          u16* C  = (fc0 < 4096) ? (u16*)C0 : (u16*)C1;
          const int ldc  = (fc0 < 4096) ? DIM : KVD;
          const int ccol = (fc0 < 4096) ? col : col - 4096;
          const int i4 = ((col & 127) >> 1) << 2;        // boundaries %128==0
          #pragma unroll
          for (int r = 0; r < 4; ++r){
            const float v = acc[i][j][r];
            const float p = __shfl_xor(v, 1);            // partner col (li^1)
            const int srow = srow0 + r;
            const float cs = rf[(size_t)srow*256 + i4];
            const float sn = rf[(size_t)srow*256 + i4 + 1];
            const float o = (col & 1) ? (v*cs + p*sn) : (v*cs - p*sn);
            C[(size_t)srow*ldc + ccol] = f2bf(o);
          }
        } else {                           // V -> transposed write Vt[1024][2048]
          u16* C = (u16*)C2;
          ushort4 o;
          o.x = f2bf(acc[i][j][0]); o.y = f2bf(acc[i][j][1]);
          o.z = f2bf(acc[i][j][2]); o.w = f2bf(acc[i][j][3]);
          *(ushort4*)&C[(size_t)(col - 5120)*SEQ + srow0] = o;
        }
      }
    }
  }
}

// ---------------- causal GQA flash attention (2 q-groups / wave, R12) --------
// Grid 512 (16 z x 32 heads). Block covers 128 q-rows (q-tile-pair z); wave w
// owns rows {qbase+w*16.., qbase+64+w*16..}. Each K/V frag ds_read feeds BOTH
// groups' MFMAs. R12: COMPLEMENTARY-PAIR grid mapping — k=bid>>5,
// z = (k<8) ? 15-k : k-8, so round-robin CU pairs (bid c, c+256) get z values
// (15-k, k): per-CU work = 34 tiles CONSTANT (R11's exact-fill pairing spread
// 20..48 tiles — the critical path). Longest blocks still dispatch first.
__global__ __launch_bounds__(256) void flash_attn(const u16* __restrict__ Q,
                                                  const u16* __restrict__ Kg,
                                                  const u16* __restrict__ Vt,
                                                  u16* __restrict__ O){
  __shared__ bf16x8 smK[2][64*16];                // 32 KB (swizzled)
  __shared__ bf16x8 smV[2][128*8];                // 32 KB (swizzled)
  __shared__ __align__(16) u16 smP[4][2][16*64];  // 16 KB: per-wave, per-group P
  const int bid = blockIdx.x;
  const int h   = bid & 31;
  const int kk_ = bid >> 5;
  const int qt2 = (kk_ < 8) ? (15 - kk_) : (kk_ - 8);   // complementary pairing
  const int g   = h >> 2;
  const int t = threadIdx.x, w = t >> 6, l = t & 63;
  const int lg = l >> 4, li = l & 15;
  const int qbase = qt2*128;

  bf16x8 qf0[4], qf1[4];
  {
    const u16* qr0 = Q + (size_t)(qbase + w*16 + li)*DIM + h*HD;
    const u16* qr1 = qr0 + (size_t)64*DIM;
    #pragma unroll
    for (int kc = 0; kc < 4; ++kc){
      qf0[kc] = *(const bf16x8*)(qr0 + kc*32 + lg*8);
      qf1[kc] = *(const bf16x8*)(qr1 + kc*32 + lg*8);
    }
  }
  f32x4 accO0[8] = {}, accO1[8] = {};
  float mrun0 = -1e30f, lsum0 = 0.f, mrun1 = -1e30f, lsum1 = 0.f;
  const float SC = 0.08838834764831845f * 1.4426950408889634f;  // scale*log2(e)
  const int ktd0 = 2*qt2;          // group-0 diagonal tile (group-1: ktd0+1)
  const int nkt  = 2*qt2 + 2;

  const int ksrow = t >> 4, ksslot = t & 15;
  const int vsrow = t >> 3, vsslot = t & 7;
  auto stage = [&](int kt, int b){
    #pragma unroll
    for (int j = 0; j < 4; ++j){
      const int krow = j*16 + ksrow;
      const int ksl = (ksslot & 8) | ((ksslot ^ (krow & 7)) & 7);
      gl_lds16(Kg + (size_t)(kt*64 + krow)*KVD + g*HD + ksl*8, (char*)&smK[b][0] + j*4096 + w*1024);
      const int vrow = j*32 + vsrow;
      const int vsl = (vsslot ^ (vrow & 7)) & 7;
      gl_lds16(Vt + (size_t)(g*HD + vrow)*SEQ + kt*64 + vsl*8, (char*)&smV[b][0] + j*4096 + w*1024);
    }
  };

  stage(0, 0);
  int buf = 0;
  u16* pw0 = &smP[w][0][0];
  u16* pw1 = &smP[w][1][0];

// per-group online softmax with defer-max; full=true masks the whole tile
// (P written as zeros -> PV adds 0; defer-max skips rescale since mx=-1e30).
#define SM(sv, mrunX, lsumX, accX, pwX, diag, full) { \
    float p_[4][4]; \
    _Pragma("unroll") \
    for (int nj = 0; nj < 4; ++nj) \
      _Pragma("unroll") \
      for (int r = 0; r < 4; ++r) p_[nj][r] = sv[nj][r] * SC; \
    if (full){ \
      _Pragma("unroll") \
      for (int nj = 0; nj < 4; ++nj) \
        _Pragma("unroll") \
        for (int r = 0; r < 4; ++r) p_[nj][r] = -1e30f; \
    } else if (diag){ \
      const int qloc = w*16 + li; \
      _Pragma("unroll") \
      for (int nj = 0; nj < 4; ++nj) \
        _Pragma("unroll") \
        for (int r = 0; r < 4; ++r) \
          if (nj*16 + lg*4 + r > qloc) p_[nj][r] = -1e30f; \
    } \
    float mx = p_[0][0]; \
    _Pragma("unroll") \
    for (int nj = 0; nj < 4; ++nj) \
      _Pragma("unroll") \
      for (int r = 0; r < 4; ++r) mx = fmaxf(mx, p_[nj][r]); \
    mx = fmaxf(mx, __shfl_xor(mx, 16)); \
    mx = fmaxf(mx, __shfl_xor(mx, 32)); \
    if (!__all(mx - mrunX <= 8.f)){ \
      const float mnew = fmaxf(mrunX, mx); \
      const float alpha = exp2f(mrunX - mnew); \
      lsumX *= alpha; \
      float al[4]; \
      _Pragma("unroll") \
      for (int r = 0; r < 4; ++r) al[r] = __shfl(alpha, (l & 48) | (lg*4 + r)); \
      _Pragma("unroll") \
      for (int dj = 0; dj < 8; ++dj) \
        _Pragma("unroll") \
        for (int r = 0; r < 4; ++r) accX[dj][r] *= al[r]; \
      mrunX = mnew; \
    } \
    float s_ = 0.f; \
    _Pragma("unroll") \
    for (int nj = 0; nj < 4; ++nj) \
      _Pragma("unroll") \
      for (int r = 0; r < 4; ++r){ p_[nj][r] = exp2f(p_[nj][r] - mrunX); s_ += p_[nj][r]; } \
    s_ += __shfl_xor(s_, 16); \
    s_ += __shfl_xor(s_, 32); \
    lsumX += s_; \
    _Pragma("unroll") \
    for (int nj = 0; nj < 4; ++nj){ \
      const int c = nj*2 + (lg >> 1); \
      uint2 v; v.x = pack2bf(p_[nj][0], p_[nj][1]); v.y = pack2bf(p_[nj][2], p_[nj][3]); \
      *(uint2*)((char*)pwX + li*128 + ((c ^ (li & 7)) << 4) + ((lg & 1) << 3)) = v; \
    } }

  for (int kt = 0; kt < nkt; ++kt){
    __syncthreads();                      // implicit vmcnt(0): tile-kt stage done
    if (kt + 1 < nkt) stage(kt + 1, buf ^ 1);

    // S^T = K Q^T for both groups: each kf read feeds 2 MFMAs
    f32x4 s0[4] = {}, s1[4] = {};
    __builtin_amdgcn_s_setprio(1);
    #pragma unroll
    for (int kc = 0; kc < 4; ++kc){
      #pragma unroll
      for (int nj = 0; nj < 4; ++nj){
        const int R = nj*16 + li;
        int sl = lg + 4*kc;
        sl = (sl & 8) | ((sl ^ (R & 7)) & 7);
        const bf16x8 kf = smK[buf][R*16 + sl];
        s1[nj] = __builtin_amdgcn_mfma_f32_16x16x32_bf16(kf, qf1[kc], s1[nj], 0, 0, 0);
        s0[nj] = __builtin_amdgcn_mfma_f32_16x16x32_bf16(kf, qf0[kc], s0[nj], 0, 0, 0);
      }
    }
    __builtin_amdgcn_s_setprio(0);

    SM(s1, mrun1, lsum1, accO1, pw1, (kt == ktd0 + 1), false)
    SM(s0, mrun0, lsum0, accO0, pw0, (kt == ktd0),     (kt > ktd0))

    // O += P V: each vf read feeds 2 MFMAs (P0 is zeros on group-0's tail tile)
    __builtin_amdgcn_s_setprio(1);
    #pragma unroll
    for (int kc2 = 0; kc2 < 2; ++kc2){
      const bf16x8 pf1 = *(const bf16x8*)((char*)pw1 + li*128 + (((kc2*4 + lg) ^ (li & 7)) << 4));
      const bf16x8 pf0 = *(const bf16x8*)((char*)pw0 + li*128 + (((kc2*4 + lg) ^ (li & 7)) << 4));
      #pragma unroll
      for (int dj = 0; dj < 8; ++dj){
        const int R = dj*16 + li;
        const bf16x8 vf = smV[buf][R*8 + ((lg + 4*kc2) ^ (R & 7))];
        accO1[dj] = __builtin_amdgcn_mfma_f32_16x16x32_bf16(pf1, vf, accO1[dj], 0, 0, 0);
        accO0[dj] = __builtin_amdgcn_mfma_f32_16x16x32_bf16(pf0, vf, accO0[dj], 0, 0, 0);
      }
    }
    __builtin_amdgcn_s_setprio(0);
    buf ^= 1;
  }
#undef SM

  // epilogue: divide by row sums, write both groups
  float linv0[4], linv1[4];
  #pragma unroll
  for (int r = 0; r < 4; ++r){
    linv0[r] = 1.f / __shfl(lsum0, (l & 48) | (lg*4 + r));
    linv1[r] = 1.f / __shfl(lsum1, (l & 48) | (lg*4 + r));
  }
  #pragma unroll
  for (int dj = 0; dj < 8; ++dj)
    #pragma unroll
    for (int r = 0; r < 4; ++r){
      const size_t row0 = (size_t)(qbase + w*16 + lg*4 + r);
      O[row0*DIM + h*HD + dj*16 + li]        = f2bf(accO0[dj][r] * linv0[r]);
      O[(row0 + 64)*DIM + h*HD + dj*16 + li] = f2bf(accO1[dj][r] * linv1[r]);
    }
}

// -----------------------------------------------------------------------------
extern "C" void kernel_launch(void* const* d_in, const int* in_sizes, int n_in,
                              void* d_out, int out_size, void* d_ws, size_t ws_size,
                              hipStream_t stream){
  const float* x  = (const float*)d_in[0];
  const float* wq = (const float*)d_in[1];
  const float* wk = (const float*)d_in[2];
  const float* wv = (const float*)d_in[3];
  const float* wo = (const float*)d_in[4];
  const float* rf = (const float*)d_in[5];
  // d_in[6] = start_pos (unused by the reference)
  float* out = (float*)d_out;

  char* ws = (char*)d_ws;
  size_t off = 0;
  auto alloc = [&](size_t nbytes){ void* p = ws + off; off += (nbytes + 255) & ~(size_t)255; return p; };
  u16* xb  = (u16*)alloc((size_t)SEQ*DIM*2);
  u16* wqb = (u16*)alloc((size_t)DIM*DIM*2);   // wqb/wkb/wvb contiguous => B[6144][4096]
  u16* wkb = (u16*)alloc((size_t)KVD*DIM*2);
  u16* wvb = (u16*)alloc((size_t)KVD*DIM*2);
  u16* wob = (u16*)alloc((size_t)DIM*DIM*2);
  u16* Qb  = (u16*)alloc((size_t)SEQ*DIM*2);
  u16* K8  = (u16*)alloc((size_t)SEQ*KVD*2);
  u16* Vtr = (u16*)alloc((size_t)KVD*SEQ*2);
  u16* AO  = (u16*)alloc((size_t)SEQ*DIM*2);
  float* P1 = (float*)wqb;   // reuse: wqb is dead after the QKV GEMM (32 MB)

  cvt_all<<<49152, 256, 0, stream>>>(x, wq, wk, wv, wo, xb, wqb, wkb, wvb, wob);

  // Fused QKV projection + RoPE + V^T (256 blocks = 8bm x 32bn, BN=192)
  gemmP<3, 0><<<256, 512, 0, stream>>>(xb, wqb, Qb, K8, Vtr, rf, nullptr);

  // Flash attention: 512 blocks (16 z x 32 heads), complementary-pair mapping
  flash_attn<<<SEQ/128 * NH, 256, 0, stream>>>(Qb, K8, Vtr, AO);

  // O projection, split-K=2 (256 blocks = 8bm x 2ks x 16bn, BN=256)
  gemmP<4, 1><<<256, 512, 0, stream>>>(AO, wob, out, nullptr, nullptr, nullptr, P1);
  add_f32<<<8192, 256, 0, stream>>>(out, P1);
}

// Round 13
// 305.430 us; speedup vs baseline: 1.1260x; 1.1260x over previous
//
#include <hip/hip_runtime.h>
#include <stdint.h>

#define DIM 4096
#define NH 32
#define NKV 8
#define HD 128
#define SEQ 2048
#define KVD 1024  // NKV*HD

typedef unsigned short u16;
typedef __attribute__((ext_vector_type(8))) short bf16x8;   // 8 bf16 in 4 VGPRs
typedef __attribute__((ext_vector_type(4))) float f32x4;

__device__ __forceinline__ float bf2f(u16 v){
  union { unsigned u; float f; } c; c.u = ((unsigned)v) << 16; return c.f;
}
__device__ __forceinline__ u16 f2bf(float f){
  union { float f; unsigned u; } c; c.f = f;
  unsigned u = c.u;
  u += 0x7FFF + ((u >> 16) & 1);   // RNE
  return (u16)(u >> 16);
}
__device__ __forceinline__ unsigned pack2bf(float a, float b){
  return (unsigned)f2bf(a) | ((unsigned)f2bf(b) << 16);
}

__device__ __forceinline__ void gl_lds16(const void* g, void* l){
  __builtin_amdgcn_global_load_lds((const __attribute__((address_space(1))) void*)g,
                                   (__attribute__((address_space(3))) void*)l, 16, 0, 0);
}

#define VM3 asm volatile("s_waitcnt vmcnt(3)" ::: "memory")
#define VM2 asm volatile("s_waitcnt vmcnt(2)" ::: "memory")
#define VM0 asm volatile("s_waitcnt vmcnt(0)" ::: "memory")
#define LGKM0 asm volatile("s_waitcnt lgkmcnt(0)" ::: "memory")
#define SB0 __builtin_amdgcn_sched_barrier(0)
#define BAR __builtin_amdgcn_s_barrier()

// ---------------- fused fp32 -> bf16 conversion (one launch, 5 segments) -----
__global__ void cvt_all(const float* __restrict__ x,  const float* __restrict__ wq,
                        const float* __restrict__ wk, const float* __restrict__ wv,
                        const float* __restrict__ wo,
                        u16* __restrict__ xb,  u16* __restrict__ wqb,
                        u16* __restrict__ wkb, u16* __restrict__ wvb,
                        u16* __restrict__ wob){
  const int b = blockIdx.x;
  const float* in; u16* out; int base;
  if      (b <  8192){ in = x;  out = xb;  base = b; }
  else if (b < 24576){ in = wq; out = wqb; base = b - 8192; }
  else if (b < 28672){ in = wk; out = wkb; base = b - 24576; }
  else if (b < 32768){ in = wv; out = wvb; base = b - 28672; }
  else               { in = wo; out = wob; base = b - 32768; }
  const int i = (base*256 + threadIdx.x)*4;
  float4 v = *(const float4*)(in + i);
  ushort4 o;
  o.x = f2bf(v.x); o.y = f2bf(v.y); o.z = f2bf(v.z); o.w = f2bf(v.w);
  *(ushort4*)(out + i) = o;
}

// ---------------- out += partial (f32x4, exact grid) --------------------------
__global__ void add_f32(float* __restrict__ out, const float* __restrict__ p){
  const int i = blockIdx.x*256 + threadIdx.x;
  float4 a = ((const float4*)out)[i];
  const float4 b = ((const float4*)p)[i];
  a.x += b.x; a.y += b.y; a.z += b.z; a.w += b.w;
  ((float4*)out)[i] = a;
}

// ---------------- m201-style 4-phase pipelined NT GEMM ------------------------
// (unchanged from R9 - see R9 comments for the wait-slack bookkeeping)
template<int BUNITS, int EPI>
__global__ __launch_bounds__(512, 2) void gemmP(const u16* __restrict__ A,
    const u16* __restrict__ B, void* __restrict__ C0, void* __restrict__ C1,
    void* __restrict__ C2, const float* __restrict__ rf, float* __restrict__ Cp){
  constexpr int BN = BUNITS*64;
  __shared__ __align__(16) char lds[65536 + BUNITS*16384];  // A[2][256][128B] | B[2][BN][128B]
  const int t = threadIdx.x, w = t >> 6, l = t & 63;
  const int lg = l >> 4, li = l & 15;
  const int wr = w >> 2, wc = w & 3;
  const int idx = ((int)blockIdx.x & 7)*32 + ((int)blockIdx.x >> 3);  // XCD swizzle (nwg=256)

  int bm, bn, kbase, nt, ks = 0;
  if (EPI == 0){ bm = idx & 7; bn = idx >> 3; kbase = 0; nt = 64; }
  else         { bm = idx & 7; ks = (idx >> 3) & 1; bn = idx >> 4; kbase = ks*2048; nt = 32; }
  const u16* Ab = A + (size_t)bm*256*DIM;
  const u16* Bb = B + (size_t)bn*BN*DIM;

  auto stA = [&](int k0, int abase, int u){
    const int r = u*64 + (t >> 3);
    gl_lds16(Ab + (size_t)r*DIM + k0 + (((t & 7) ^ (r & 7)) << 3),
             lds + abase + u*8192 + (t >> 3)*128 + (t & 7)*16);
  };
  auto stB = [&](int k0, int bbase, int u){
    const int r = u*64 + (t >> 3);
    gl_lds16(Bb + (size_t)r*DIM + k0 + (((t & 7) ^ (r & 7)) << 3),
             lds + bbase + u*8192 + (t >> 3)*128 + (t & 7)*16);
  };

  f32x4 acc[8][BUNITS] = {};
  bf16x8 bfr[BUNITS][2];   // B-frags held across all 4 phases of a tile

#define PH(p, ...) { \
    bf16x8 af[2][2]; \
    _Pragma("unroll") \
    for (int q = 0; q < 2; ++q){ \
      const int R = wr*128 + (2*(p)+q)*16 + li; \
      af[q][0] = *(const bf16x8*)(ldsA + R*128 + (( lg    ^ (R & 7)) << 4)); \
      af[q][1] = *(const bf16x8*)(ldsA + R*128 + (((lg+4) ^ (R & 7)) << 4)); \
    } \
    if ((p) == 0){ \
      _Pragma("unroll") \
      for (int j = 0; j < BUNITS; ++j){ \
        const int R = wc*(BUNITS*16) + j*16 + li; \
        bfr[j][0] = *(const bf16x8*)(ldsB + R*128 + (( lg    ^ (R & 7)) << 4)); \
        bfr[j][1] = *(const bf16x8*)(ldsB + R*128 + (((lg+4) ^ (R & 7)) << 4)); \
      } \
    } \
    __VA_ARGS__; \
    BAR; LGKM0; SB0; \
    __builtin_amdgcn_s_setprio(1); \
    _Pragma("unroll") \
    for (int q = 0; q < 2; ++q) \
      _Pragma("unroll") \
      for (int j = 0; j < BUNITS; ++j){ \
        acc[2*(p)+q][j] = __builtin_amdgcn_mfma_f32_16x16x32_bf16(af[q][0], bfr[j][0], acc[2*(p)+q][j], 0, 0, 0); \
        acc[2*(p)+q][j] = __builtin_amdgcn_mfma_f32_16x16x32_bf16(af[q][1], bfr[j][1], acc[2*(p)+q][j], 0, 0, 0); \
      } \
    __builtin_amdgcn_s_setprio(0); \
    BAR; }

  // prologue: stage tile 0 with A1,A3 LAST; VM2 leaves {A1,A3} (the invariant)
  #pragma unroll
  for (int u = 0; u < BUNITS; ++u) stB(kbase, 65536, u);
  stA(kbase, 0, 0); stA(kbase, 0, 2);
  stA(kbase, 0, 1); stA(kbase, 0, 3);
  VM2; BAR;

  for (int tt = 0; tt < nt; ++tt){
    const int buf = tt & 1, b2 = buf ^ 1;
    const int k1 = kbase + (tt+1)*64;
    const bool pf = (tt + 1 < nt);
    const char* ldsA = lds + buf*32768;
    const char* ldsB = lds + 65536 + buf*BUNITS*8192;
    const int a2 = b2*32768, b2o = 65536 + b2*BUNITS*8192;

    PH(0, if (pf){ stB(k1, b2o, 0); stB(k1, b2o, 1); stB(k1, b2o, 2); })
    PH(1, if (pf){ VM3; if constexpr (BUNITS == 4) stB(k1, b2o, 3);
                   stA(k1, a2, 0); stA(k1, a2, 2); }
          else   { VM0; })
    PH(2, if (pf){ stA(k1, a2, 1); })
    PH(3, if (pf){ stA(k1, a2, 3); VM2; })
  }
#undef PH

  // ---------------- epilogue ----------------
  if (EPI == 1){
    float* C = (float*)(ks ? Cp : C0);
    #pragma unroll
    for (int i = 0; i < 8; ++i){
      const int srow = bm*256 + wr*128 + i*16 + lg*4;
      #pragma unroll
      for (int j = 0; j < BUNITS; ++j){
        const int col = bn*BN + wc*(BUNITS*16) + j*16 + li;
        #pragma unroll
        for (int r = 0; r < 4; ++r)
          C[(size_t)(srow + r)*DIM + col] = acc[i][j][r];
      }
    }
  } else {
    #pragma unroll
    for (int i = 0; i < 8; ++i){
      const int srow0 = bm*256 + wr*128 + i*16 + lg*4;
      #pragma unroll
      for (int j = 0; j < BUNITS; ++j){
        const int fc0 = bn*BN + wc*(BUNITS*16) + j*16;   // frag base col (16-aligned)
        const int col = fc0 + li;
        if (fc0 < 5120){                   // Q (cols<4096) or K: fused RoPE
          u16* C  = (fc0 < 4096) ? (u16*)C0 : (u16*)C1;
          const int ldc  = (fc0 < 4096) ? DIM : KVD;
          const int ccol = (fc0 < 4096) ? col : col - 4096;
          const int i4 = ((col & 127) >> 1) << 2;        // boundaries %128==0
          #pragma unroll
          for (int r = 0; r < 4; ++r){
            const float v = acc[i][j][r];
            const float p = __shfl_xor(v, 1);            // partner col (li^1)
            const int srow = srow0 + r;
            const float cs = rf[(size_t)srow*256 + i4];
            const float sn = rf[(size_t)srow*256 + i4 + 1];
            const float o = (col & 1) ? (v*cs + p*sn) : (v*cs - p*sn);
            C[(size_t)srow*ldc + ccol] = f2bf(o);
          }
        } else {                           // V -> transposed write Vt[1024][2048]
          u16* C = (u16*)C2;
          ushort4 o;
          o.x = f2bf(acc[i][j][0]); o.y = f2bf(acc[i][j][1]);
          o.z = f2bf(acc[i][j][2]); o.w = f2bf(acc[i][j][3]);
          *(ushort4*)&C[(size_t)(col - 5120)*SEQ + srow0] = o;
        }
      }
    }
  }
}

// ---------------- causal GQA flash attention (R13 = R9-proven + T13 + T5) ----
// 1D grid 1024, longest-qt blocks first: qt = 31 - bid/32, h = bid%32.
// 4 waves; wave w owns q rows [qt*64+16w, +16). Swapped QK^T (mfma(K,Q)) so
// each lane owns one full q-row (q = li): in-lane softmax + 2-shfl reduce.
// K/V double-buffered in LDS, next tile staged before compute. R13 adds:
// T13 defer-max (skip rescale when __all(mx-mrun<=8); wave-uniform condition
// since row-max is uniform over a q-row's 4 lanes) and T5 setprio on MFMA.
__global__ __launch_bounds__(256) void flash_attn(const u16* __restrict__ Q,
                                                  const u16* __restrict__ Kg,
                                                  const u16* __restrict__ Vt,
                                                  u16* __restrict__ O){
  __shared__ bf16x8 smK[2][64*16];              // [64 rows][16 slots], swizzled; 2x16KB
  __shared__ bf16x8 smV[2][128*8];              // [128 rows][8 slots], swizzled; 2x16KB
  __shared__ __align__(16) u16 smP[4][16*64];   // per-wave P, XOR-swizzled 16B chunks; 8KB
  const int bid = blockIdx.x;
  const int h  = bid & 31;
  const int qt = 31 - (bid >> 5);
  const int g  = h >> 2;
  const int t = threadIdx.x, w = t >> 6, l = t & 63;
  const int lg = l >> 4, li = l & 15;

  bf16x8 qf[4];                                  // Q row (w*16+li), d-chunks
  {
    const u16* qrow = Q + (size_t)(qt*64 + w*16 + li)*DIM + h*HD;
    #pragma unroll
    for (int kc = 0; kc < 4; ++kc)
      qf[kc] = *(const bf16x8*)(qrow + kc*32 + lg*8);
  }
  f32x4 accO[8] = {};
  float mrun = -1e30f, lsum = 0.f;
  const float SC = 0.08838834764831845f * 1.4426950408889634f;  // scale * log2(e)

  const int ksrow = t >> 4, ksslot = t & 15;  // K staging: 256B rows, 16 slots
  const int vsrow = t >> 3, vsslot = t & 7;   // V staging: 128B rows, 8 slots

  auto stage = [&](int kt, int b){
    #pragma unroll
    for (int j = 0; j < 4; ++j){
      const int krow = j*16 + ksrow;
      const int ksl = (ksslot & 8) | ((ksslot ^ (krow & 7)) & 7);
      gl_lds16(Kg + (size_t)(kt*64 + krow)*KVD + g*HD + ksl*8, (char*)&smK[b][0] + j*4096 + w*1024);
      const int vrow = j*32 + vsrow;
      const int vsl = (vsslot ^ (vrow & 7)) & 7;
      gl_lds16(Vt + (size_t)(g*HD + vrow)*SEQ + kt*64 + vsl*8, (char*)&smV[b][0] + j*4096 + w*1024);
    }
  };

  stage(0, 0);
  int buf = 0;
  u16* pw = &smP[w][0];

  for (int kt = 0; kt <= qt; ++kt){
    __syncthreads();                      // implicit vmcnt(0): tile-kt stage done
    if (kt < qt) stage(kt + 1, buf ^ 1);  // overlap next stage with this compute

    // S^T = K Q^T : lane holds S[kk = nj*16+lg*4+r][q = li]
    f32x4 sacc[4] = {};
    __builtin_amdgcn_s_setprio(1);
    #pragma unroll
    for (int kc = 0; kc < 4; ++kc){
      #pragma unroll
      for (int nj = 0; nj < 4; ++nj){
        const int R = nj*16 + li;
        int sl = lg + 4*kc;
        sl = (sl & 8) | ((sl ^ (R & 7)) & 7);
        sacc[nj] = __builtin_amdgcn_mfma_f32_16x16x32_bf16(smK[buf][R*16 + sl], qf[kc], sacc[nj], 0, 0, 0);
      }
    }
    __builtin_amdgcn_s_setprio(0);
    float p[4][4];
    #pragma unroll
    for (int nj = 0; nj < 4; ++nj)
      #pragma unroll
      for (int r = 0; r < 4; ++r)
        p[nj][r] = sacc[nj][r] * SC;
    if (kt == qt){                         // mask only on the diagonal tile
      const int qloc = w*16 + li;
      #pragma unroll
      for (int nj = 0; nj < 4; ++nj)
        #pragma unroll
        for (int r = 0; r < 4; ++r)
          if (nj*16 + lg*4 + r > qloc) p[nj][r] = -1e30f;
    }
    // online softmax, row q=li fully in this lane (16 vals) + lanes l^16,l^32
    float mx = p[0][0];
    #pragma unroll
    for (int nj = 0; nj < 4; ++nj)
      #pragma unroll
      for (int r = 0; r < 4; ++r) mx = fmaxf(mx, p[nj][r]);
    mx = fmaxf(mx, __shfl_xor(mx, 16));
    mx = fmaxf(mx, __shfl_xor(mx, 32));
    // T13 defer-max: skip rescale while max growth <= 8 (log2 units); P then
    // bounded by 2^8 -> lsum <= 128*256, fine in f32.
    if (!__all(mx - mrun <= 8.f)){
      const float mnew = fmaxf(mrun, mx);
      const float alpha = exp2f(mrun - mnew);
      lsum *= alpha;
      float al[4];
      #pragma unroll
      for (int r = 0; r < 4; ++r) al[r] = __shfl(alpha, (l & 48) | (lg*4 + r));
      #pragma unroll
      for (int dj = 0; dj < 8; ++dj)
        #pragma unroll
        for (int r = 0; r < 4; ++r) accO[dj][r] *= al[r];
      mrun = mnew;
    }
    float s = 0.f;
    #pragma unroll
    for (int nj = 0; nj < 4; ++nj)
      #pragma unroll
      for (int r = 0; r < 4; ++r){ p[nj][r] = exp2f(p[nj][r] - mrun); s += p[nj][r]; }
    s += __shfl_xor(s, 16);
    s += __shfl_xor(s, 32);
    lsum += s;
    // write P (row q=li, kk consecutive per write): 4x 8B swizzled ds_write
    #pragma unroll
    for (int nj = 0; nj < 4; ++nj){
      const int c = nj*2 + (lg >> 1);
      uint2 v; v.x = pack2bf(p[nj][0], p[nj][1]); v.y = pack2bf(p[nj][2], p[nj][3]);
      *(uint2*)((char*)pw + li*128 + ((c ^ (li & 7)) << 4) + ((lg & 1) << 3)) = v;
    }
    // O += P V   (A-frag: P row li, kk = kc2*32+lg*8+j; B-frag: Vt row d)
    __builtin_amdgcn_s_setprio(1);
    #pragma unroll
    for (int kc2 = 0; kc2 < 2; ++kc2){
      const bf16x8 pf = *(const bf16x8*)((char*)pw + li*128 + (((kc2*4 + lg) ^ (li & 7)) << 4));
      #pragma unroll
      for (int dj = 0; dj < 8; ++dj){
        const int R = dj*16 + li;
        const bf16x8 vf = smV[buf][R*8 + ((lg + 4*kc2) ^ (R & 7))];
        accO[dj] = __builtin_amdgcn_mfma_f32_16x16x32_bf16(pf, vf, accO[dj], 0, 0, 0);
      }
    }
    __builtin_amdgcn_s_setprio(0);
    buf ^= 1;
  }
  // epilogue: divide by row sum (row q=lg*4+r), write
  float linv[4];
  #pragma unroll
  for (int r = 0; r < 4; ++r) linv[r] = 1.f / __shfl(lsum, (l & 48) | (lg*4 + r));
  #pragma unroll
  for (int dj = 0; dj < 8; ++dj)
    #pragma unroll
    for (int r = 0; r < 4; ++r)
      O[(size_t)(qt*64 + w*16 + lg*4 + r)*DIM + h*HD + dj*16 + li] = f2bf(accO[dj][r] * linv[r]);
}

// -----------------------------------------------------------------------------
extern "C" void kernel_launch(void* const* d_in, const int* in_sizes, int n_in,
                              void* d_out, int out_size, void* d_ws, size_t ws_size,
                              hipStream_t stream){
  const float* x  = (const float*)d_in[0];
  const float* wq = (const float*)d_in[1];
  const float* wk = (const float*)d_in[2];
  const float* wv = (const float*)d_in[3];
  const float* wo = (const float*)d_in[4];
  const float* rf = (const float*)d_in[5];
  // d_in[6] = start_pos (unused by the reference)
  float* out = (float*)d_out;

  char* ws = (char*)d_ws;
  size_t off = 0;
  auto alloc = [&](size_t nbytes){ void* p = ws + off; off += (nbytes + 255) & ~(size_t)255; return p; };
  u16* xb  = (u16*)alloc((size_t)SEQ*DIM*2);
  u16* wqb = (u16*)alloc((size_t)DIM*DIM*2);   // wqb/wkb/wvb contiguous => B[6144][4096]
  u16* wkb = (u16*)alloc((size_t)KVD*DIM*2);
  u16* wvb = (u16*)alloc((size_t)KVD*DIM*2);
  u16* wob = (u16*)alloc((size_t)DIM*DIM*2);
  u16* Qb  = (u16*)alloc((size_t)SEQ*DIM*2);
  u16* K8  = (u16*)alloc((size_t)SEQ*KVD*2);
  u16* Vtr = (u16*)alloc((size_t)KVD*SEQ*2);
  u16* AO  = (u16*)alloc((size_t)SEQ*DIM*2);
  float* P1 = (float*)wqb;   // reuse: wqb is dead after the QKV GEMM (32 MB)

  cvt_all<<<49152, 256, 0, stream>>>(x, wq, wk, wv, wo, xb, wqb, wkb, wvb, wob);

  // Fused QKV projection + RoPE + V^T (256 blocks = 8bm x 32bn, BN=192)
  gemmP<3, 0><<<256, 512, 0, stream>>>(xb, wqb, Qb, K8, Vtr, rf, nullptr);

  // Flash attention: 1024 blocks (32 qt x 32 heads), longest-first
  flash_attn<<<SEQ/64 * NH, 256, 0, stream>>>(Qb, K8, Vtr, AO);

  // O projection, split-K=2 (256 blocks = 8bm x 2ks x 16bn, BN=256)
  gemmP<4, 1><<<256, 512, 0, stream>>>(AO, wob, out, nullptr, nullptr, nullptr, P1);
  add_f32<<<8192, 256, 0, stream>>>(out, P1);
}